// Round 3
// baseline (764.077 us; speedup 1.0000x reference)
//
#include <hip/hip_runtime.h>

// Problem constants (from reference)
#define NN 38332          // nodes
#define FF 544            // input features
#define CC 128            // channels
#define LL 4              // gcn layers
#define EE (NN*16)        // edges (613312)
#define PP 38333          // POI_LEN (output size)

typedef __attribute__((ext_vector_type(8))) short short8v;
typedef __attribute__((ext_vector_type(4))) float floatx4;

static __device__ __forceinline__ float lrelu(float x) {
    return x >= 0.f ? x : 0.01f * x;
}

// fp32 -> bf16 round-to-nearest-even (bit trick)
static __device__ __forceinline__ short f2bf(float f) {
    unsigned u = __float_as_uint(f);
    unsigned r = (u + 0x7fffu + ((u >> 16) & 1u)) >> 16;
    return (short)r;
}
static __device__ __forceinline__ float bf2f(short s) {
    return __uint_as_float(((unsigned)(unsigned short)s) << 16);
}

// async global->LDS, 16B per lane. ldst must be WAVE-UNIFORM base; HW writes
// lane i's 16B at ldst + i*16 (m97/m104 semantics).
static __device__ __forceinline__ void async_ld16(const void* gsrc, void* ldst) {
    __builtin_amdgcn_global_load_lds(
        (const __attribute__((address_space(1))) unsigned int*)gsrc,
        (__attribute__((address_space(3))) unsigned int*)ldst,
        16, 0, 0);
}

// ---------------------------------------------------------------------------
// Prep: val[i] = emb[poi[i/128]*128 + i%128]; deg init 1 (self loop); fill=0
// ---------------------------------------------------------------------------
__global__ __launch_bounds__(256) void k_prep(const float* __restrict__ feature,
                                              const float* __restrict__ emb,
                                              float* __restrict__ val,
                                              float* __restrict__ deg,
                                              int* __restrict__ fill, int n) {
    int i = blockIdx.x * 256 + threadIdx.x;
    if (i >= n) return;
    int row = i >> 7;
    int ch  = i & 127;
    int id  = (int)feature[row * FF];
    val[i]  = emb[id * CC + ch];
    deg[i]  = 1.0f;
    fill[i] = 0;
}

__global__ __launch_bounds__(256) void k_deg(const int* __restrict__ dst,
                                             float* __restrict__ deg, int e) {
    int i = blockIdx.x * 256 + threadIdx.x;
    if (i >= e) return;
    atomicAdd(&deg[dst[i]], 1.0f);
}

__global__ __launch_bounds__(256) void k_dinv(const float* __restrict__ deg,
                                              float* __restrict__ dinv, int n) {
    int i = blockIdx.x * 256 + threadIdx.x;
    if (i >= n) return;
    dinv[i] = rsqrtf(deg[i]);
}

__global__ __launch_bounds__(1024) void k_scan(const float* __restrict__ deg,
                                               int* __restrict__ rowptr, int n) {
    __shared__ int sums[1024];
    int t = threadIdx.x;
    int chunk = (n + 1023) / 1024;
    int s = t * chunk;
    int e = min(n, s + chunk);
    int local = 0;
    for (int i = s; i < e; i++) local += (int)deg[i] - 1;
    sums[t] = local;
    __syncthreads();
    for (int off = 1; off < 1024; off <<= 1) {
        int v = (t >= off) ? sums[t - off] : 0;
        __syncthreads();
        sums[t] += v;
        __syncthreads();
    }
    int run = (t == 0) ? 0 : sums[t - 1];
    for (int i = s; i < e; i++) {
        rowptr[i] = run;
        run += (int)deg[i] - 1;
    }
    if (t == 1023) rowptr[n] = run;
}

__global__ __launch_bounds__(256) void k_fill(const int* __restrict__ src,
                                              const int* __restrict__ dst,
                                              const float* __restrict__ dinv,
                                              const int* __restrict__ rowptr,
                                              int* __restrict__ fill,
                                              int* __restrict__ csr_src,
                                              float* __restrict__ csr_w, int e) {
    int i = blockIdx.x * 256 + threadIdx.x;
    if (i >= e) return;
    int d = dst[i], s = src[i];
    int pos = rowptr[d] + atomicAdd(&fill[d], 1);
    csr_src[pos] = s;
    csr_w[pos]   = dinv[s] * dinv[d];
}

// ---------------------------------------------------------------------------
// B split precompute: W[K][128] fp32 -> Bt_hi/Bt_lo[128][K] bf16 (transposed)
// ---------------------------------------------------------------------------
__global__ __launch_bounds__(256) void k_bsplit(const float* __restrict__ W,
                                                short* __restrict__ Bth,
                                                short* __restrict__ Btl, int K) {
    int idx = blockIdx.x * 256 + threadIdx.x;
    if (idx >= K * 128) return;
    int bn = idx / K, k = idx - bn * K;
    float w = W[k * CC + bn];
    short h = f2bf(w);
    Bth[idx] = h;
    Btl[idx] = f2bf(w - bf2f(h));
}

// ---------------------------------------------------------------------------
// FF GEMM (input layer, K=544): round-2 structure, in-kernel split of A.
// ---------------------------------------------------------------------------
template <int K, bool SUBST>
__global__ __launch_bounds__(256) void k_gemm_mfma(const float* __restrict__ A,
                                                   int lda,
                                                   const float* __restrict__ val,
                                                   const short* __restrict__ Bth,
                                                   const short* __restrict__ Btl,
                                                   float* __restrict__ H, int n) {
    __shared__ __align__(16) short Ah[64 * 40];
    __shared__ __align__(16) short Al[64 * 40];
    __shared__ __align__(16) short Bh[128 * 40];
    __shared__ __align__(16) short Bl[128 * 40];

    const int t    = threadIdx.x;
    const int i0   = blockIdx.x * 64;
    const int lane = t & 63;
    const int w    = t >> 6;
    const int fr   = lane & 15;
    const int sel  = lane >> 4;
    const int m0   = w * 16;

    floatx4 acc[8];
    #pragma unroll
    for (int j = 0; j < 8; j++) acc[j] = (floatx4){0.f, 0.f, 0.f, 0.f};

    const int ar = t >> 2, aseg = t & 3;

    for (int k0 = 0; k0 < K; k0 += 32) {
        {
            int i = i0 + ar;
            float v[8];
            if (i < n) {
                const float* ap = A + (size_t)i * lda + k0 + aseg * 8;
                float4 p0 = *(const float4*)ap;
                float4 p1 = *(const float4*)(ap + 4);
                v[0] = p0.x; v[1] = p0.y; v[2] = p0.z; v[3] = p0.w;
                v[4] = p1.x; v[5] = p1.y; v[6] = p1.z; v[7] = p1.w;
                if (SUBST && k0 == 0 && aseg == 0) v[0] = val[i];
            } else {
                #pragma unroll
                for (int j = 0; j < 8; j++) v[j] = 0.f;
            }
            short8v hv, lv;
            #pragma unroll
            for (int j = 0; j < 8; j++) {
                short h = f2bf(v[j]);
                hv[j] = h;
                lv[j] = f2bf(v[j] - bf2f(h));
            }
            *(short8v*)&Ah[ar * 40 + aseg * 8] = hv;
            *(short8v*)&Al[ar * 40 + aseg * 8] = lv;
        }
        #pragma unroll
        for (int j = 0; j < 2; j++) {
            int c  = t + j * 256;
            int bn = c >> 2, bs = c & 3;
            const short* gh = Bth + (size_t)bn * K + k0 + bs * 8;
            const short* gl = Btl + (size_t)bn * K + k0 + bs * 8;
            *(short8v*)&Bh[bn * 40 + bs * 8] = *(const short8v*)gh;
            *(short8v*)&Bl[bn * 40 + bs * 8] = *(const short8v*)gl;
        }
        __syncthreads();

        short8v ah = *(short8v*)&Ah[(m0 + fr) * 40 + sel * 8];
        short8v al = *(short8v*)&Al[(m0 + fr) * 40 + sel * 8];
        #pragma unroll
        for (int nt = 0; nt < 8; nt++) {
            short8v bh = *(short8v*)&Bh[(nt * 16 + fr) * 40 + sel * 8];
            short8v bl = *(short8v*)&Bl[(nt * 16 + fr) * 40 + sel * 8];
            acc[nt] = __builtin_amdgcn_mfma_f32_16x16x32_bf16(ah, bh, acc[nt], 0, 0, 0);
            acc[nt] = __builtin_amdgcn_mfma_f32_16x16x32_bf16(ah, bl, acc[nt], 0, 0, 0);
            acc[nt] = __builtin_amdgcn_mfma_f32_16x16x32_bf16(al, bh, acc[nt], 0, 0, 0);
        }
        __syncthreads();
    }

    #pragma unroll
    for (int nt = 0; nt < 8; nt++) {
        int col = nt * 16 + fr;
        #pragma unroll
        for (int r = 0; r < 4; r++) {
            int row = i0 + m0 + sel * 4 + r;
            if (row < n) H[(size_t)row * CC + col] = acc[nt][r];
        }
    }
}

// ---------------------------------------------------------------------------
// C-GEMM (K=128): A pre-split bf16 hi/lo (from k_row). B-frags in VGPRs
// (whole 128x128 weight per wave's n-slice). A staged via global_load_lds
// into lane-ordered frames [ksub][row] of 16B -> conflict-free ds_read_b128.
// Block: 256 thr, BM=64, wave w owns cols [32w,32w+32).
// ---------------------------------------------------------------------------
__global__ __launch_bounds__(256) void k_gemm128(const short* __restrict__ Xh,
                                                 const short* __restrict__ Xl,
                                                 const short* __restrict__ Bth,
                                                 const short* __restrict__ Btl,
                                                 float* __restrict__ H, int n) {
    __shared__ __align__(16) short Ah_s[2048];   // 4 KB: frames [sel*64+row]*8
    __shared__ __align__(16) short Al_s[2048];
    const int t    = threadIdx.x;
    const int w    = t >> 6;
    const int lane = t & 63;
    const int fr   = lane & 15;
    const int sel  = lane >> 4;
    const int i0   = blockIdx.x * 64;

    // --- B fragments -> registers (L2/L3-resident after first blocks) ---
    short8v bh[2][4], bl[2][4];
    #pragma unroll
    for (int nt = 0; nt < 2; nt++) {
        int nidx = (w * 2 + nt) * 16 + fr;
        #pragma unroll
        for (int kit = 0; kit < 4; kit++) {
            bh[nt][kit] = *(const short8v*)&Bth[nidx * 128 + kit * 32 + sel * 8];
            bl[nt][kit] = *(const short8v*)&Btl[nidx * 128 + kit * 32 + sel * 8];
        }
    }

    floatx4 acc[4][2];
    #pragma unroll
    for (int mt = 0; mt < 4; mt++)
        #pragma unroll
        for (int nt = 0; nt < 2; nt++)
            acc[mt][nt] = (floatx4){0.f, 0.f, 0.f, 0.f};

    int rA = i0 + lane;
    if (rA > n - 1) rA = n - 1;              // clamp pad rows (never stored)
    const short* gh = Xh + (size_t)rA * 128 + w * 8;
    const short* gl = Xl + (size_t)rA * 128 + w * 8;
    short* lh = &Ah_s[w * 512];              // wave-uniform LDS base
    short* ll = &Al_s[w * 512];

    #pragma unroll
    for (int kit = 0; kit < 4; kit++) {
        async_ld16(gh + kit * 32, lh);       // lane i -> lh + i*16
        async_ld16(gl + kit * 32, ll);
        __syncthreads();                     // drains vmcnt -> LDS visible
        short8v ah[4], al[4];
        #pragma unroll
        for (int mt = 0; mt < 4; mt++) {
            int off = (sel * 64 + mt * 16 + fr) * 8;
            ah[mt] = *(const short8v*)&Ah_s[off];
            al[mt] = *(const short8v*)&Al_s[off];
        }
        #pragma unroll
        for (int mt = 0; mt < 4; mt++)
            #pragma unroll
            for (int nt = 0; nt < 2; nt++) {
                acc[mt][nt] = __builtin_amdgcn_mfma_f32_16x16x32_bf16(ah[mt], bh[nt][kit], acc[mt][nt], 0, 0, 0);
                acc[mt][nt] = __builtin_amdgcn_mfma_f32_16x16x32_bf16(ah[mt], bl[nt][kit], acc[mt][nt], 0, 0, 0);
                acc[mt][nt] = __builtin_amdgcn_mfma_f32_16x16x32_bf16(al[mt], bh[nt][kit], acc[mt][nt], 0, 0, 0);
            }
        __syncthreads();                     // protect LDS before next stage
    }

    #pragma unroll
    for (int mt = 0; mt < 4; mt++)
        #pragma unroll
        for (int nt = 0; nt < 2; nt++) {
            int col = (w * 2 + nt) * 16 + fr;
            #pragma unroll
            for (int r = 0; r < 4; r++) {
                int row = i0 + mt * 16 + sel * 4 + r;
                if (row < n) H[(size_t)row * CC + col] = acc[mt][nt][r];
            }
        }
}

// ---------------------------------------------------------------------------
// Row gather v2: 256 thr = 8 rows x 32 lanes, float4 per lane.
// out = bias + self + sum(H[src]*w); MODE 0: lrelu(t)  MODE 1: lrelu(t)+t.
// Writes X pre-split to bf16 hi/lo for the next GEMM.
// ---------------------------------------------------------------------------
template <int MODE>
__global__ __launch_bounds__(256) void k_row(const float* __restrict__ H,
                                             const int* __restrict__ rowptr,
                                             const int* __restrict__ csr_src,
                                             const float* __restrict__ csr_w,
                                             const float* __restrict__ dinv,
                                             const float* __restrict__ bias,
                                             short* __restrict__ Xh,
                                             short* __restrict__ Xl, int n) {
    const int lr  = threadIdx.x >> 5;        // local row 0..7
    const int c   = threadIdx.x & 31;        // col quad
    const int row = blockIdx.x * 8 + lr;
    if (row >= n) return;
    const float di = dinv[row];
    const float4* H4 = (const float4*)H;
    float4 b4 = ((const float4*)bias)[c];
    float4 s4 = H4[(size_t)row * 32 + c];
    float dd = di * di;
    float a0 = b4.x + s4.x * dd;
    float a1 = b4.y + s4.y * dd;
    float a2 = b4.z + s4.z * dd;
    float a3 = b4.w + s4.w * dd;
    const int e1 = rowptr[row + 1];
    for (int e = rowptr[row]; e < e1; e++) {
        int   s = csr_src[e];                // broadcast across 32 lanes
        float wv = csr_w[e];
        float4 hv = H4[(size_t)s * 32 + c];
        a0 += hv.x * wv; a1 += hv.y * wv; a2 += hv.z * wv; a3 += hv.w * wv;
    }
    float vals[4] = {a0, a1, a2, a3};
    short hh[4], ll[4];
    #pragma unroll
    for (int j = 0; j < 4; j++) {
        float tt = vals[j];
        float r  = lrelu(tt);
        float x  = MODE ? (r + tt) : r;
        short h  = f2bf(x);
        hh[j] = h;
        ll[j] = f2bf(x - bf2f(h));
    }
    size_t o = (size_t)row * 128 + c * 4;
    *(short4*)&Xh[o] = make_short4(hh[0], hh[1], hh[2], hh[3]);
    *(short4*)&Xl[o] = make_short4(ll[0], ll[1], ll[2], ll[3]);
}

// x @ W_out ([N,128] @ [128,1]), x reconstructed from split
__global__ __launch_bounds__(256) void k_wout(const short* __restrict__ Xh,
                                              const short* __restrict__ Xl,
                                              const float* __restrict__ Wout,
                                              float* __restrict__ gpre, int n) {
    int gid  = blockIdx.x * 256 + threadIdx.x;
    int wid  = gid >> 6;
    int lane = threadIdx.x & 63;
    if (wid >= n) return;
    size_t o = (size_t)wid * CC + lane;
    float x0 = bf2f(Xh[o])      + bf2f(Xl[o]);
    float x1 = bf2f(Xh[o + 64]) + bf2f(Xl[o + 64]);
    float p = x0 * Wout[lane] + x1 * Wout[64 + lane];
    #pragma unroll
    for (int off = 32; off > 0; off >>= 1) p += __shfl_down(p, off, 64);
    if (lane == 0) gpre[wid] = p;
}

__global__ __launch_bounds__(256) void k_row1(const float* __restrict__ gpre,
                                              const int* __restrict__ rowptr,
                                              const int* __restrict__ csr_src,
                                              const float* __restrict__ csr_w,
                                              const float* __restrict__ dinv,
                                              const float* __restrict__ bout,
                                              float* __restrict__ g, int n) {
    int i = blockIdx.x * 256 + threadIdx.x;
    if (i >= n) return;
    float di = dinv[i];
    float acc = bout[0] + gpre[i] * di * di;
    int e1 = rowptr[i + 1];
    for (int e = rowptr[i]; e < e1; e++)
        acc += gpre[csr_src[e]] * csr_w[e];
    g[i] = lrelu(acc);
}

__global__ void k_hacc_init(const float* __restrict__ bfc1, float* __restrict__ hacc) {
    hacc[threadIdx.x] = bfc1[threadIdx.x];
}

// g[N] @ W_fc1[N,128] : 512 blocks x 256 thr (2 row streams), LDS reduce
__global__ __launch_bounds__(256) void k_fc1(const float* __restrict__ g,
                                             const float* __restrict__ Wfc1,
                                             float* __restrict__ hacc, int n) {
    __shared__ float red[256];
    int c = threadIdx.x & 127;
    int p = threadIdx.x >> 7;
    int nb = gridDim.x;
    int chunk = (n + nb - 1) / nb;
    int s = blockIdx.x * chunk;
    int e = min(n, s + chunk);
    float acc = 0.f;
    for (int i = s + p; i < e; i += 2)
        acc += g[i] * Wfc1[(size_t)i * CC + c];
    red[threadIdx.x] = acc;
    __syncthreads();
    if (p == 0) atomicAdd(&hacc[c], red[c] + red[128 + c]);
}

__global__ __launch_bounds__(256) void k_fc2(const float* __restrict__ hacc,
                                             const float* __restrict__ Wfc2,
                                             const float* __restrict__ bfc2,
                                             float* __restrict__ out, int P) {
    __shared__ float sh[128];
    int t = threadIdx.x;
    if (t < 128) { float v = hacc[t]; sh[t] = v > 0.f ? v : 0.f; }
    __syncthreads();
    int k = blockIdx.x * 256 + t;
    if (k >= P) return;
    float acc = bfc2[k];
    #pragma unroll 8
    for (int j = 0; j < 128; j++)
        acc += sh[j] * Wfc2[(size_t)j * P + k];
    out[k] = acc > 0.f ? acc : 0.f;
}

// ---------------------------------------------------------------------------
extern "C" void kernel_launch(void* const* d_in, const int* in_sizes, int n_in,
                              void* d_out, int out_size, void* d_ws, size_t ws_size,
                              hipStream_t stream) {
    const float* feature = (const float*)d_in[0];
    const int*   eidx  = (const int*)d_in[2];
    const int*   e_src = eidx;
    const int*   e_dst = eidx + EE;
    const float* emb   = (const float*)d_in[3];
    const float* W_in  = (const float*)d_in[4];
    const float* b_in  = (const float*)d_in[5];
    const float* W_gcn = (const float*)d_in[6];
    const float* b_gcn = (const float*)d_in[7];
    const float* W_out = (const float*)d_in[8];
    const float* b_out = (const float*)d_in[9];
    const float* W_fc1 = (const float*)d_in[10];
    const float* b_fc1 = (const float*)d_in[11];
    const float* W_fc2 = (const float*)d_in[12];
    const float* b_fc2 = (const float*)d_in[13];
    float* out = (float*)d_out;

    float* w = (float*)d_ws;
    size_t off = 0;
    auto take = [&](size_t elems) -> float* {
        float* p = w + off;
        off += (elems + 63) & ~(size_t)63;
        return p;
    };
    float* val     = take(NN);
    float* deg     = take(NN);
    float* dinv    = take(NN);
    int*   rowptr  = (int*)take(NN + 1);
    int*   fill    = (int*)take(NN);
    int*   csr_src = (int*)take(EE);
    float* csr_w   = take(EE);
    float* bufH    = take((size_t)NN * CC);            // H (fp32)
    short* Xh      = (short*)take((size_t)NN * CC / 2); // X split hi (bf16)
    short* Xl      = (short*)take((size_t)NN * CC / 2); // X split lo
    float* gpre    = take(NN);
    float* g       = take(NN);
    float* hacc    = take(128);
    short* bt_in_h  = (short*)take(FF * CC / 2);
    short* bt_in_l  = (short*)take(FF * CC / 2);
    short* bt_gcn_h = (short*)take((size_t)LL * CC * CC / 2);
    short* bt_gcn_l = (short*)take((size_t)LL * CC * CC / 2);
    (void)ws_size; (void)in_sizes; (void)n_in; (void)out_size;

    const int gN  = (NN + 255) / 256;
    const int gE  = (EE + 255) / 256;
    const int gBM = (NN + 63) / 64;
    const int gR  = (NN + 7) / 8;

    // --- weight splits ---
    k_bsplit<<<(FF * CC + 255) / 256, 256, 0, stream>>>(W_in, bt_in_h, bt_in_l, FF);
    for (int l = 0; l < LL; l++)
        k_bsplit<<<(CC * CC + 255) / 256, 256, 0, stream>>>(
            W_gcn + (size_t)l * CC * CC,
            bt_gcn_h + (size_t)l * CC * CC, bt_gcn_l + (size_t)l * CC * CC, CC);

    // --- graph preprocessing: CSR by dst + symmetric norm ---
    k_prep<<<gN, 256, 0, stream>>>(feature, emb, val, deg, fill, NN);
    k_deg<<<gE, 256, 0, stream>>>(e_dst, deg, EE);
    k_dinv<<<gN, 256, 0, stream>>>(deg, dinv, NN);
    k_scan<<<1, 1024, 0, stream>>>(deg, rowptr, NN);
    k_fill<<<gE, 256, 0, stream>>>(e_src, e_dst, dinv, rowptr, fill,
                                   csr_src, csr_w, EE);

    // --- input layer ---
    k_gemm_mfma<FF, true><<<gBM, 256, 0, stream>>>(feature, FF, val,
                                                   bt_in_h, bt_in_l, bufH, NN);
    k_row<0><<<gR, 256, 0, stream>>>(bufH, rowptr, csr_src, csr_w, dinv, b_in,
                                     Xh, Xl, NN);

    // --- 4 GcnUnits ---
    for (int l = 0; l < LL; l++) {
        k_gemm128<<<gBM, 256, 0, stream>>>(Xh, Xl,
            bt_gcn_h + (size_t)l * CC * CC, bt_gcn_l + (size_t)l * CC * CC,
            bufH, NN);
        k_row<1><<<gR, 256, 0, stream>>>(bufH, rowptr, csr_src, csr_w, dinv,
                                         b_gcn + (size_t)l * CC, Xh, Xl, NN);
    }

    // --- output conv (C=1) ---
    k_wout<<<(NN * 64 + 255) / 256, 256, 0, stream>>>(Xh, Xl, W_out, gpre, NN);
    k_row1<<<gN, 256, 0, stream>>>(gpre, rowptr, csr_src, csr_w, dinv, b_out,
                                   g, NN);

    // --- FC head ---
    k_hacc_init<<<1, 128, 0, stream>>>(b_fc1, hacc);
    k_fc1<<<512, 256, 0, stream>>>(g, W_fc1, hacc, NN);
    k_fc2<<<(PP + 255) / 256, 256, 0, stream>>>(hacc, W_fc2, b_fc2, out, PP);
}

// Round 4
// 715.732 us; speedup vs baseline: 1.0675x; 1.0675x over previous
//
#include <hip/hip_runtime.h>

// Problem constants (from reference)
#define NN 38332          // nodes
#define FF 544            // input features
#define CC 128            // channels
#define LL 4              // gcn layers
#define EE (NN*16)        // edges (613312)
#define PP 38333          // POI_LEN (output size)

typedef __attribute__((ext_vector_type(8))) short short8v;
typedef __attribute__((ext_vector_type(4))) float floatx4;

static __device__ __forceinline__ float lrelu(float x) {
    return x >= 0.f ? x : 0.01f * x;
}

// fp32 -> bf16 round-to-nearest-even (bit trick)
static __device__ __forceinline__ short f2bf(float f) {
    unsigned u = __float_as_uint(f);
    unsigned r = (u + 0x7fffu + ((u >> 16) & 1u)) >> 16;
    return (short)r;
}
static __device__ __forceinline__ float bf2f(short s) {
    return __uint_as_float(((unsigned)(unsigned short)s) << 16);
}

// async global->LDS, 16B per lane. ldst must be WAVE-UNIFORM base; HW writes
// lane i's 16B at ldst + i*16 (m97/m104 semantics).
static __device__ __forceinline__ void async_ld16(const void* gsrc, void* ldst) {
    __builtin_amdgcn_global_load_lds(
        (const __attribute__((address_space(1))) unsigned int*)gsrc,
        (__attribute__((address_space(3))) unsigned int*)ldst,
        16, 0, 0);
}

// ---------------------------------------------------------------------------
// Prep: val[i] = emb[poi[i/128]*128 + i%128]; deg init 1 (self loop); fill=0
// ---------------------------------------------------------------------------
__global__ __launch_bounds__(256) void k_prep(const float* __restrict__ feature,
                                              const float* __restrict__ emb,
                                              float* __restrict__ val,
                                              float* __restrict__ deg,
                                              int* __restrict__ fill, int n) {
    int i = blockIdx.x * 256 + threadIdx.x;
    if (i >= n) return;
    int row = i >> 7;
    int ch  = i & 127;
    int id  = (int)feature[row * FF];
    val[i]  = emb[id * CC + ch];
    deg[i]  = 1.0f;
    fill[i] = 0;
}

__global__ __launch_bounds__(256) void k_deg(const int* __restrict__ dst,
                                             float* __restrict__ deg, int e) {
    int i = blockIdx.x * 256 + threadIdx.x;
    if (i >= e) return;
    atomicAdd(&deg[dst[i]], 1.0f);
}

__global__ __launch_bounds__(256) void k_dinv(const float* __restrict__ deg,
                                              float* __restrict__ dinv, int n) {
    int i = blockIdx.x * 256 + threadIdx.x;
    if (i >= n) return;
    dinv[i] = rsqrtf(deg[i]);
}

__global__ __launch_bounds__(1024) void k_scan(const float* __restrict__ deg,
                                               int* __restrict__ rowptr, int n) {
    __shared__ int sums[1024];
    int t = threadIdx.x;
    int chunk = (n + 1023) / 1024;
    int s = t * chunk;
    int e = min(n, s + chunk);
    int local = 0;
    for (int i = s; i < e; i++) local += (int)deg[i] - 1;
    sums[t] = local;
    __syncthreads();
    for (int off = 1; off < 1024; off <<= 1) {
        int v = (t >= off) ? sums[t - off] : 0;
        __syncthreads();
        sums[t] += v;
        __syncthreads();
    }
    int run = (t == 0) ? 0 : sums[t - 1];
    for (int i = s; i < e; i++) {
        rowptr[i] = run;
        run += (int)deg[i] - 1;
    }
    if (t == 1023) rowptr[n] = run;
}

__global__ __launch_bounds__(256) void k_fill(const int* __restrict__ src,
                                              const int* __restrict__ dst,
                                              const float* __restrict__ dinv,
                                              const int* __restrict__ rowptr,
                                              int* __restrict__ fill,
                                              int* __restrict__ csr_src,
                                              float* __restrict__ csr_w, int e) {
    int i = blockIdx.x * 256 + threadIdx.x;
    if (i >= e) return;
    int d = dst[i], s = src[i];
    int pos = rowptr[d] + atomicAdd(&fill[d], 1);
    csr_src[pos] = s;
    csr_w[pos]   = dinv[s] * dinv[d];
}

// ---------------------------------------------------------------------------
// B split precompute: W[K][128] fp32 -> Bt_hi/Bt_lo[128][K] bf16 (transposed)
// ---------------------------------------------------------------------------
__global__ __launch_bounds__(256) void k_bsplit(const float* __restrict__ W,
                                                short* __restrict__ Bth,
                                                short* __restrict__ Btl, int K) {
    int idx = blockIdx.x * 256 + threadIdx.x;
    if (idx >= K * 128) return;
    int bn = idx / K, k = idx - bn * K;
    float w = W[k * CC + bn];
    short h = f2bf(w);
    Bth[idx] = h;
    Btl[idx] = f2bf(w - bf2f(h));
}

// ---------------------------------------------------------------------------
// FF GEMM (input layer, K=544): BM=64, BK=32, register-prefetch double buffer.
// Wave w: rows [16w,16w+16), all 128 cols (8 n-tiles).
// ---------------------------------------------------------------------------
template <int K, bool SUBST>
__global__ __launch_bounds__(256) void k_gemm_mfma(const float* __restrict__ A,
                                                   int lda,
                                                   const float* __restrict__ val,
                                                   const short* __restrict__ Bth,
                                                   const short* __restrict__ Btl,
                                                   float* __restrict__ H, int n) {
    __shared__ __align__(16) short Ah[64 * 40];
    __shared__ __align__(16) short Al[64 * 40];
    __shared__ __align__(16) short Bh[128 * 40];
    __shared__ __align__(16) short Bl[128 * 40];

    const int t    = threadIdx.x;
    const int i0   = blockIdx.x * 64;
    const int lane = t & 63;
    const int w    = t >> 6;
    const int fr   = lane & 15;
    const int sel  = lane >> 4;
    const int m0   = w * 16;

    floatx4 acc[8];
    #pragma unroll
    for (int j = 0; j < 8; j++) acc[j] = (floatx4){0.f, 0.f, 0.f, 0.f};

    // staging roles
    const int ar = t >> 2, aseg = t & 3;        // A: row, 8-float segment
    const int bn = t >> 1, bhalf = t & 1;       // B: n-row, 16-short half
    const int i = i0 + ar;
    const bool iok = (i < n);
    const float* apb = A + (size_t)i * lda + aseg * 8;
    const short* gbh = Bth + (size_t)bn * K + bhalf * 16;
    const short* gbl = Btl + (size_t)bn * K + bhalf * 16;

    float4  pa0 = make_float4(0, 0, 0, 0), pa1 = make_float4(0, 0, 0, 0);
    short8v pbh0, pbh1, pbl0, pbl1;

    // issue k0 = 0
    if (iok) { pa0 = *(const float4*)apb; pa1 = *(const float4*)(apb + 4); }
    pbh0 = *(const short8v*)gbh;       pbh1 = *(const short8v*)(gbh + 8);
    pbl0 = *(const short8v*)gbl;       pbl1 = *(const short8v*)(gbl + 8);

    constexpr int NIT = K / 32;
    for (int kc = 0; kc < NIT; kc++) {
        // --- commit prefetched tile to LDS ---
        {
            float v[8] = {pa0.x, pa0.y, pa0.z, pa0.w, pa1.x, pa1.y, pa1.z, pa1.w};
            if (SUBST && kc == 0 && aseg == 0) v[0] = iok ? val[i] : 0.f;
            short8v hv, lv;
            #pragma unroll
            for (int j = 0; j < 8; j++) {
                short h = f2bf(v[j]);
                hv[j] = h;
                lv[j] = f2bf(v[j] - bf2f(h));
            }
            *(short8v*)&Ah[ar * 40 + aseg * 8] = hv;
            *(short8v*)&Al[ar * 40 + aseg * 8] = lv;
            *(short8v*)&Bh[bn * 40 + bhalf * 16]     = pbh0;
            *(short8v*)&Bh[bn * 40 + bhalf * 16 + 8] = pbh1;
            *(short8v*)&Bl[bn * 40 + bhalf * 16]     = pbl0;
            *(short8v*)&Bl[bn * 40 + bhalf * 16 + 8] = pbl1;
        }
        // --- issue next tile's global loads (complete during MFMA) ---
        if (kc + 1 < NIT) {
            int k0n = (kc + 1) * 32;
            if (iok) {
                pa0 = *(const float4*)(apb + k0n);
                pa1 = *(const float4*)(apb + k0n + 4);
            }
            pbh0 = *(const short8v*)(gbh + k0n);
            pbh1 = *(const short8v*)(gbh + k0n + 8);
            pbl0 = *(const short8v*)(gbl + k0n);
            pbl1 = *(const short8v*)(gbl + k0n + 8);
        }
        __syncthreads();

        short8v ah = *(short8v*)&Ah[(m0 + fr) * 40 + sel * 8];
        short8v al = *(short8v*)&Al[(m0 + fr) * 40 + sel * 8];
        #pragma unroll
        for (int nt = 0; nt < 8; nt++) {
            short8v bh = *(short8v*)&Bh[(nt * 16 + fr) * 40 + sel * 8];
            short8v bl = *(short8v*)&Bl[(nt * 16 + fr) * 40 + sel * 8];
            acc[nt] = __builtin_amdgcn_mfma_f32_16x16x32_bf16(ah, bh, acc[nt], 0, 0, 0);
            acc[nt] = __builtin_amdgcn_mfma_f32_16x16x32_bf16(ah, bl, acc[nt], 0, 0, 0);
            acc[nt] = __builtin_amdgcn_mfma_f32_16x16x32_bf16(al, bh, acc[nt], 0, 0, 0);
        }
        __syncthreads();
    }

    #pragma unroll
    for (int nt = 0; nt < 8; nt++) {
        int col = nt * 16 + fr;
        #pragma unroll
        for (int r = 0; r < 4; r++) {
            int row = i0 + m0 + sel * 4 + r;
            if (row < n) H[(size_t)row * CC + col] = acc[nt][r];
        }
    }
}

// ---------------------------------------------------------------------------
// C-GEMM (K=128): B-frags in VGPRs; ENTIRE 64x128 A-tile (hi+lo) staged via
// 8 global_load_lds up front -> ONE barrier, then 96 uninterrupted MFMAs.
// LDS frames: [kit*4 + w] of 512 shorts; wave w stages k-slice [kit*32+8w,+8).
// ---------------------------------------------------------------------------
__global__ __launch_bounds__(256) void k_gemm128(const short* __restrict__ Xh,
                                                 const short* __restrict__ Xl,
                                                 const short* __restrict__ Bth,
                                                 const short* __restrict__ Btl,
                                                 float* __restrict__ H, int n) {
    __shared__ __align__(16) short Ah_s[16 * 512];   // 16 KB
    __shared__ __align__(16) short Al_s[16 * 512];   // 16 KB
    const int t    = threadIdx.x;
    const int w    = t >> 6;
    const int lane = t & 63;
    const int fr   = lane & 15;
    const int sel  = lane >> 4;
    const int i0   = blockIdx.x * 64;

    // --- B fragments -> registers ---
    short8v bh[2][4], bl[2][4];
    #pragma unroll
    for (int nt = 0; nt < 2; nt++) {
        int nidx = (w * 2 + nt) * 16 + fr;
        #pragma unroll
        for (int kit = 0; kit < 4; kit++) {
            bh[nt][kit] = *(const short8v*)&Bth[nidx * 128 + kit * 32 + sel * 8];
            bl[nt][kit] = *(const short8v*)&Btl[nidx * 128 + kit * 32 + sel * 8];
        }
    }

    floatx4 acc[4][2];
    #pragma unroll
    for (int mt = 0; mt < 4; mt++)
        #pragma unroll
        for (int nt = 0; nt < 2; nt++)
            acc[mt][nt] = (floatx4){0.f, 0.f, 0.f, 0.f};

    int rA = i0 + lane;
    if (rA > n - 1) rA = n - 1;              // clamp pad rows (never stored)
    const short* gh = Xh + (size_t)rA * 128 + w * 8;
    const short* gl = Xl + (size_t)rA * 128 + w * 8;

    #pragma unroll
    for (int kit = 0; kit < 4; kit++) {
        async_ld16(gh + kit * 32, &Ah_s[(kit * 4 + w) * 512]);
        async_ld16(gl + kit * 32, &Al_s[(kit * 4 + w) * 512]);
    }
    __syncthreads();                          // single drain for all staging

    #pragma unroll
    for (int kit = 0; kit < 4; kit++) {
        short8v ah[4], al[4];
        #pragma unroll
        for (int mt = 0; mt < 4; mt++) {
            int off = (kit * 4 + sel) * 512 + (mt * 16 + fr) * 8;
            ah[mt] = *(const short8v*)&Ah_s[off];
            al[mt] = *(const short8v*)&Al_s[off];
        }
        #pragma unroll
        for (int mt = 0; mt < 4; mt++)
            #pragma unroll
            for (int nt = 0; nt < 2; nt++) {
                acc[mt][nt] = __builtin_amdgcn_mfma_f32_16x16x32_bf16(ah[mt], bh[nt][kit], acc[mt][nt], 0, 0, 0);
                acc[mt][nt] = __builtin_amdgcn_mfma_f32_16x16x32_bf16(ah[mt], bl[nt][kit], acc[mt][nt], 0, 0, 0);
                acc[mt][nt] = __builtin_amdgcn_mfma_f32_16x16x32_bf16(al[mt], bh[nt][kit], acc[mt][nt], 0, 0, 0);
            }
    }

    #pragma unroll
    for (int mt = 0; mt < 4; mt++)
        #pragma unroll
        for (int nt = 0; nt < 2; nt++) {
            int col = (w * 2 + nt) * 16 + fr;
            #pragma unroll
            for (int r = 0; r < 4; r++) {
                int row = i0 + mt * 16 + sel * 4 + r;
                if (row < n) H[(size_t)row * CC + col] = acc[mt][nt][r];
            }
        }
}

// ---------------------------------------------------------------------------
// Row gather v3: ONE WAVE (64-thr block) per dst row, float2 per lane.
// LDS-staged index batches (64 at a time) -> all gather addresses known
// up front -> deep memory-level parallelism. Uniform trip count per block.
// Writes X pre-split to bf16 hi/lo for the next GEMM.
// ---------------------------------------------------------------------------
template <int MODE>
__global__ __launch_bounds__(64) void k_row(const float* __restrict__ H,
                                            const int* __restrict__ rowptr,
                                            const int* __restrict__ csr_src,
                                            const float* __restrict__ csr_w,
                                            const float* __restrict__ dinv,
                                            const float* __restrict__ bias,
                                            short* __restrict__ Xh,
                                            short* __restrict__ Xl, int n) {
    __shared__ int   s_idx[64];
    __shared__ float s_w[64];
    const int row = blockIdx.x;
    const int l   = threadIdx.x;             // 0..63 -> channels (2l, 2l+1)
    const float di = dinv[row];
    const float dd = di * di;
    const float2* H2 = (const float2*)H;
    float2 b2 = ((const float2*)bias)[l];
    float2 s2 = H2[(size_t)row * 64 + l];
    float a0 = b2.x + s2.x * dd;
    float a1 = b2.y + s2.y * dd;
    const int rs = rowptr[row], re = rowptr[row + 1];
    for (int base = rs; base < re; base += 64) {
        int m = re - base; if (m > 64) m = 64;
        __syncthreads();
        if (l < m) { s_idx[l] = csr_src[base + l]; s_w[l] = csr_w[base + l]; }
        __syncthreads();
        for (int j = 0; j < m; j++) {
            float2 hv = H2[(size_t)s_idx[j] * 64 + l];
            float  wv = s_w[j];
            a0 += hv.x * wv;
            a1 += hv.y * wv;
        }
    }
    float r0 = lrelu(a0), r1 = lrelu(a1);
    float x0 = MODE ? (r0 + a0) : r0;
    float x1 = MODE ? (r1 + a1) : r1;
    short h0 = f2bf(x0), h1 = f2bf(x1);
    short lo0 = f2bf(x0 - bf2f(h0)), lo1 = f2bf(x1 - bf2f(h1));
    size_t o = (size_t)row * 128 + l * 2;
    *(short2*)&Xh[o] = make_short2(h0, h1);
    *(short2*)&Xl[o] = make_short2(lo0, lo1);
}

// x @ W_out ([N,128] @ [128,1]), x reconstructed from split
__global__ __launch_bounds__(256) void k_wout(const short* __restrict__ Xh,
                                              const short* __restrict__ Xl,
                                              const float* __restrict__ Wout,
                                              float* __restrict__ gpre, int n) {
    int gid  = blockIdx.x * 256 + threadIdx.x;
    int wid  = gid >> 6;
    int lane = threadIdx.x & 63;
    if (wid >= n) return;
    size_t o = (size_t)wid * CC + lane;
    float x0 = bf2f(Xh[o])      + bf2f(Xl[o]);
    float x1 = bf2f(Xh[o + 64]) + bf2f(Xl[o + 64]);
    float p = x0 * Wout[lane] + x1 * Wout[64 + lane];
    #pragma unroll
    for (int off = 32; off > 0; off >>= 1) p += __shfl_down(p, off, 64);
    if (lane == 0) gpre[wid] = p;
}

__global__ __launch_bounds__(256) void k_row1(const float* __restrict__ gpre,
                                              const int* __restrict__ rowptr,
                                              const int* __restrict__ csr_src,
                                              const float* __restrict__ csr_w,
                                              const float* __restrict__ dinv,
                                              const float* __restrict__ bout,
                                              float* __restrict__ g, int n) {
    int i = blockIdx.x * 256 + threadIdx.x;
    if (i >= n) return;
    float di = dinv[i];
    float acc = bout[0] + gpre[i] * di * di;
    int e1 = rowptr[i + 1];
    for (int e = rowptr[i]; e < e1; e++)
        acc += gpre[csr_src[e]] * csr_w[e];
    g[i] = lrelu(acc);
}

__global__ void k_hacc_init(const float* __restrict__ bfc1, float* __restrict__ hacc) {
    hacc[threadIdx.x] = bfc1[threadIdx.x];
}

// g[N] @ W_fc1[N,128] : 512 blocks x 256 thr (2 row streams), LDS reduce
__global__ __launch_bounds__(256) void k_fc1(const float* __restrict__ g,
                                             const float* __restrict__ Wfc1,
                                             float* __restrict__ hacc, int n) {
    __shared__ float red[256];
    int c = threadIdx.x & 127;
    int p = threadIdx.x >> 7;
    int nb = gridDim.x;
    int chunk = (n + nb - 1) / nb;
    int s = blockIdx.x * chunk;
    int e = min(n, s + chunk);
    float acc = 0.f;
    for (int i = s + p; i < e; i += 2)
        acc += g[i] * Wfc1[(size_t)i * CC + c];
    red[threadIdx.x] = acc;
    __syncthreads();
    if (p == 0) atomicAdd(&hacc[c], red[c] + red[128 + c]);
}

__global__ __launch_bounds__(256) void k_fc2(const float* __restrict__ hacc,
                                             const float* __restrict__ Wfc2,
                                             const float* __restrict__ bfc2,
                                             float* __restrict__ out, int P) {
    __shared__ float sh[128];
    int t = threadIdx.x;
    if (t < 128) { float v = hacc[t]; sh[t] = v > 0.f ? v : 0.f; }
    __syncthreads();
    int k = blockIdx.x * 256 + t;
    if (k >= P) return;
    float acc = bfc2[k];
    #pragma unroll 8
    for (int j = 0; j < 128; j++)
        acc += sh[j] * Wfc2[(size_t)j * P + k];
    out[k] = acc > 0.f ? acc : 0.f;
}

// ---------------------------------------------------------------------------
extern "C" void kernel_launch(void* const* d_in, const int* in_sizes, int n_in,
                              void* d_out, int out_size, void* d_ws, size_t ws_size,
                              hipStream_t stream) {
    const float* feature = (const float*)d_in[0];
    const int*   eidx  = (const int*)d_in[2];
    const int*   e_src = eidx;
    const int*   e_dst = eidx + EE;
    const float* emb   = (const float*)d_in[3];
    const float* W_in  = (const float*)d_in[4];
    const float* b_in  = (const float*)d_in[5];
    const float* W_gcn = (const float*)d_in[6];
    const float* b_gcn = (const float*)d_in[7];
    const float* W_out = (const float*)d_in[8];
    const float* b_out = (const float*)d_in[9];
    const float* W_fc1 = (const float*)d_in[10];
    const float* b_fc1 = (const float*)d_in[11];
    const float* W_fc2 = (const float*)d_in[12];
    const float* b_fc2 = (const float*)d_in[13];
    float* out = (float*)d_out;

    float* w = (float*)d_ws;
    size_t off = 0;
    auto take = [&](size_t elems) -> float* {
        float* p = w + off;
        off += (elems + 63) & ~(size_t)63;
        return p;
    };
    float* val     = take(NN);
    float* deg     = take(NN);
    float* dinv    = take(NN);
    int*   rowptr  = (int*)take(NN + 1);
    int*   fill    = (int*)take(NN);
    int*   csr_src = (int*)take(EE);
    float* csr_w   = take(EE);
    float* bufH    = take((size_t)NN * CC);             // H (fp32)
    short* Xh      = (short*)take((size_t)NN * CC / 2); // X split hi (bf16)
    short* Xl      = (short*)take((size_t)NN * CC / 2); // X split lo
    float* gpre    = take(NN);
    float* g       = take(NN);
    float* hacc    = take(128);
    short* bt_in_h  = (short*)take(FF * CC / 2);
    short* bt_in_l  = (short*)take(FF * CC / 2);
    short* bt_gcn_h = (short*)take((size_t)LL * CC * CC / 2);
    short* bt_gcn_l = (short*)take((size_t)LL * CC * CC / 2);
    (void)ws_size; (void)in_sizes; (void)n_in; (void)out_size;

    const int gN  = (NN + 255) / 256;
    const int gE  = (EE + 255) / 256;
    const int gBM = (NN + 63) / 64;

    // --- weight splits ---
    k_bsplit<<<(FF * CC + 255) / 256, 256, 0, stream>>>(W_in, bt_in_h, bt_in_l, FF);
    for (int l = 0; l < LL; l++)
        k_bsplit<<<(CC * CC + 255) / 256, 256, 0, stream>>>(
            W_gcn + (size_t)l * CC * CC,
            bt_gcn_h + (size_t)l * CC * CC, bt_gcn_l + (size_t)l * CC * CC, CC);

    // --- graph preprocessing: CSR by dst + symmetric norm ---
    k_prep<<<gN, 256, 0, stream>>>(feature, emb, val, deg, fill, NN);
    k_deg<<<gE, 256, 0, stream>>>(e_dst, deg, EE);
    k_dinv<<<gN, 256, 0, stream>>>(deg, dinv, NN);
    k_scan<<<1, 1024, 0, stream>>>(deg, rowptr, NN);
    k_fill<<<gE, 256, 0, stream>>>(e_src, e_dst, dinv, rowptr, fill,
                                   csr_src, csr_w, EE);

    // --- input layer ---
    k_gemm_mfma<FF, true><<<gBM, 256, 0, stream>>>(feature, FF, val,
                                                   bt_in_h, bt_in_l, bufH, NN);
    k_row<0><<<NN, 64, 0, stream>>>(bufH, rowptr, csr_src, csr_w, dinv, b_in,
                                    Xh, Xl, NN);

    // --- 4 GcnUnits ---
    for (int l = 0; l < LL; l++) {
        k_gemm128<<<gBM, 256, 0, stream>>>(Xh, Xl,
            bt_gcn_h + (size_t)l * CC * CC, bt_gcn_l + (size_t)l * CC * CC,
            bufH, NN);
        k_row<1><<<NN, 64, 0, stream>>>(bufH, rowptr, csr_src, csr_w, dinv,
                                        b_gcn + (size_t)l * CC, Xh, Xl, NN);
    }

    // --- output conv (C=1) ---
    k_wout<<<(NN * 64 + 255) / 256, 256, 0, stream>>>(Xh, Xl, W_out, gpre, NN);
    k_row1<<<gN, 256, 0, stream>>>(gpre, rowptr, csr_src, csr_w, dinv, b_out,
                                   g, NN);

    // --- FC head ---
    k_hacc_init<<<1, 128, 0, stream>>>(b_fc1, hacc);
    k_fc1<<<512, 256, 0, stream>>>(g, W_fc1, hacc, NN);
    k_fc2<<<(PP + 255) / 256, 256, 0, stream>>>(hacc, W_fc2, b_fc2, out, PP);
}